// Round 1
// baseline (193.859 us; speedup 1.0000x reference)
//
#include <hip/hip_runtime.h>

// NSScan: roll(-2,-2) + 4 nested-S-scan permutations, fused + closed-form.
// Input  x_2d: (N=8, H=256, W=256, C=96) fp32, flat NHWC.
// Output: (4*N, L=H*W, C) fp32 — [h_fwd, h_bwd, v_fwd, v_bwd] stacked on axis 0.
//
// Scatter formulation: each thread owns ONE input float4 (coalesced read,
// input read exactly once = 201 MB), computes the 4 destination rows in
// closed form, writes 4 float4s (805 MB, each dst row a contiguous 384B
// chunk = 6 full 64B lines).

constexpr int N  = 8;
constexpr int H  = 256;
constexpr int W  = 256;
constexpr int C  = 96;
constexpr int L  = H * W;          // 65536
constexpr int C4 = C / 4;          // 24 float4 per row
constexpr unsigned IN_F4 = (unsigned)N * (unsigned)L * (unsigned)C4; // 12,582,912

__global__ __launch_bounds__(256)
void nss_scatter(const float4* __restrict__ in, float4* __restrict__ out) {
    unsigned t = blockIdx.x * 256u + threadIdx.x;   // grid sized exactly
    // decompose: t = ((n*H + hs)*W + ws)*C4 + c4
    unsigned c4   = t % C4;
    unsigned rowi = t / C4;            // n*H*W + hs*W + ws
    unsigned ws   = rowi & (W - 1);
    unsigned hs   = (rowi >> 8) & (H - 1);
    unsigned n    = rowi >> 16;

    float4 v = in[t];

    // roll(-2,-2): x[h][w] = x_2d[(h+2)%H][(w+2)%W]  =>  source (hs,ws)
    // lands at rolled coords (hs-2, ws-2) mod 256.
    unsigned h = (hs + H - 2) & (H - 1);
    unsigned w = (ws + W - 2) & (W - 1);

    // closed-form scan positions (stripe_width=4, %2 parity => plain parity)
    unsigned jh = h * W + ((h & 1) ? (W - 1 - w) : w);   // h_fwd
    unsigned jv = w * H + ((w & 1) ? (H - 1 - h) : h);   // v_fwd

    unsigned nL = n * (unsigned)L;
    // d=0: h_fwd, d=1: h_bwd, d=2: v_fwd, d=3: v_bwd
    out[(size_t)((0u * N * L) + nL + jh)           * C4 + c4] = v;
    out[(size_t)((1u * N * L) + nL + (L - 1 - jh)) * C4 + c4] = v;
    out[(size_t)((2u * N * L) + nL + jv)           * C4 + c4] = v;
    out[(size_t)((3u * N * L) + nL + (L - 1 - jv)) * C4 + c4] = v;
}

extern "C" void kernel_launch(void* const* d_in, const int* in_sizes, int n_in,
                              void* d_out, int out_size, void* d_ws, size_t ws_size,
                              hipStream_t stream) {
    const float4* in  = (const float4*)d_in[0];
    float4*       out = (float4*)d_out;
    unsigned blocks = IN_F4 / 256u;    // 49152, exact
    nss_scatter<<<blocks, 256, 0, stream>>>(in, out);
}

// Round 2
// 150.709 us; speedup vs baseline: 1.2863x; 1.2863x over previous
//
#include <hip/hip_runtime.h>

// NSScan: roll(-2,-2) + 4 nested-S permutations, closed-form, LDS-tiled scatter.
// Input  (8,256,256,96) fp32 NHWC; Output (32, 65536, 96) fp32.
//
// Per block: 16(h) x 8(w) pixel tile, all 96 channels (48 KiB LDS).
// Phase 1: coalesced tile load; h_fwd/h_bwd written direct from register
//          (contiguous 3 KB spans per h-row).
// Phase 2: v_fwd/v_bwd from LDS, reorganized so each w-column emits a
//          contiguous 6 KB span (16 consecutive dest rows) instead of the
//          round-1 384 B chunks at 96 KB stride.

typedef float f4 __attribute__((ext_vector_type(4)));

constexpr int N = 8, H = 256, W = 256, C4 = 24;   // C=96 -> 24 float4
constexpr int L = H * W;                           // 65536
constexpr int TH = 16, TW = 8;
constexpr int TILE_F4 = TH * TW * C4;              // 3072 float4 = 48 KiB
constexpr int THREADS = 512;
constexpr unsigned OUTPLANE = (unsigned)N * L;     // rows per direction

__global__ __launch_bounds__(THREADS)
void nss_tiled(const f4* __restrict__ in, f4* __restrict__ out) {
    __shared__ f4 lds[TILE_F4];

    unsigned bid = blockIdx.x;
    unsigned twi = bid & 31;           // 32 w-tiles
    unsigned thi = (bid >> 5) & 15;    // 16 h-tiles
    unsigned n   = bid >> 9;
    unsigned h0 = thi * TH, w0 = twi * TW;
    unsigned t = threadIdx.x;
    unsigned nbase = n << 16;          // n*L

    // ---- Phase 1: load tile (coalesced) + h_fwd/h_bwd direct writes ----
#pragma unroll
    for (int i = 0; i < TILE_F4 / THREADS; ++i) {
        unsigned idx = t + i * THREADS;
        unsigned c4 = idx % 24u;
        unsigned p  = idx / 24u;       // 0..127 : pixel in tile
        unsigned wl = p & 7u;
        unsigned hl = p >> 3;
        unsigned h = h0 + hl, w = w0 + wl;
        unsigned hs = (h + 2u) & 255u, ws = (w + 2u) & 255u;  // roll(-2,-2)
        f4 v = in[(nbase + (hs << 8) + ws) * 24u + c4];
        lds[p * 24u + c4] = v;
        unsigned dcol = (h & 1u) ? (255u - w) : w;
        unsigned jh = (h << 8) + dcol;                         // h_fwd row
        __builtin_nontemporal_store(v, &out[(0u * OUTPLANE + nbase + jh) * 24u + c4]);
        __builtin_nontemporal_store(v, &out[(1u * OUTPLANE + nbase + ((unsigned)L - 1u - jh)) * 24u + c4]);
    }
    __syncthreads();

    // ---- Phase 2: v_fwd/v_bwd from LDS, contiguous 16-row spans per w ----
#pragma unroll
    for (int i = 0; i < TILE_F4 / THREADS; ++i) {
        unsigned idx = t + i * THREADS;
        unsigned c4 = idx % 24u;
        unsigned p  = idx / 24u;
        unsigned rq = p & 15u;         // offset within the dest-row span
        unsigned wl = p >> 4;          // 0..7
        unsigned w = w0 + wl;
        unsigned rbase = (w & 1u) ? ((unsigned)H - (unsigned)TH - h0) : h0;
        unsigned r = rbase + rq;
        unsigned jv = (w << 8) + r;                            // v_fwd row
        unsigned srch = (w & 1u) ? (255u - r) : r;
        unsigned hl = srch - h0;
        f4 v = lds[(hl * 8u + wl) * 24u + c4];
        __builtin_nontemporal_store(v, &out[(2u * OUTPLANE + nbase + jv) * 24u + c4]);
        __builtin_nontemporal_store(v, &out[(3u * OUTPLANE + nbase + ((unsigned)L - 1u - jv)) * 24u + c4]);
    }
}

extern "C" void kernel_launch(void* const* d_in, const int* in_sizes, int n_in,
                              void* d_out, int out_size, void* d_ws, size_t ws_size,
                              hipStream_t stream) {
    const f4* in  = (const f4*)d_in[0];
    f4*       out = (f4*)d_out;
    // grid: 8 n  x 16 h-tiles x 32 w-tiles
    unsigned blocks = (unsigned)N * (H / TH) * (W / TW);   // 4096
    nss_tiled<<<blocks, THREADS, 0, stream>>>(in, out);
}